// Round 9
// baseline (503.462 us; speedup 1.0000x reference)
//
#include <hip/hip_runtime.h>
#include <hip/hip_bf16.h>
#include <type_traits>

typedef __hip_bfloat16 bf16;
typedef __attribute__((ext_vector_type(8))) short short8;
typedef __attribute__((ext_vector_type(4))) float floatx4;

static constexpr int kB = 8;
static constexpr int kS = 1024;
static constexpr int kE = 512;
static constexpr int kH = 8;
static constexpr int kP = 32;
static constexpr int kTok = kB * kS;   // 8192
static constexpr int kHid = 2048;

// meta layout: [0]=pm int32 flag, [1..8]=valid_len, [9]=inputs-are-fp32 flag
// ---------------------------------------------------------------- helpers
__device__ __forceinline__ void load8f(const bf16* p, float* f) {
  uint4 u = *(const uint4*)p;
  const bf16* h = (const bf16*)&u;
#pragma unroll
  for (int e = 0; e < 8; e++) f[e] = __bfloat162float(h[e]);
}
__device__ __forceinline__ void store8b(bf16* p, const float* f) {
  uint4 u;
  bf16* h = (bf16*)&u;
#pragma unroll
  for (int e = 0; e < 8; e++) h[e] = __float2bfloat16(f[e]);
  *(uint4*)p = u;
}
__device__ __forceinline__ bool is_pad(const void* pm, int flag, int idx) {
  return flag ? (((const int*)pm)[idx] != 0)
              : (((const unsigned char*)pm)[idx] != 0);
}
__device__ __forceinline__ float fast_gelu(float x) {
  float u = x * (0.7978845608f + 0.044714998f * x * x);
  float e = __expf(2.0f * u);
  float t = 1.0f - 2.0f / (e + 1.0f);
  return 0.5f * x * (1.0f + t);
}
// async global->LDS 16B DMA. dest = wave-uniform lds base + lane*16.
__device__ __forceinline__ void dma16(const bf16* g, bf16* l) {
  __builtin_amdgcn_global_load_lds(
      (const __attribute__((address_space(1))) unsigned int*)g,
      (__attribute__((address_space(3))) unsigned int*)l, 16, 0, 0);
}
// Explicit full drain (vmcnt/lgkmcnt/expcnt = 0). REQUIRED before barriers
// that hand a DMA-written LDS buffer to other waves (R6 race: global_load_lds
// has no dest VGPR, compiler waitcnt pass misses the dependence).
__device__ __forceinline__ void drain_all() { __builtin_amdgcn_s_waitcnt(0); }

// ----------------------------------------- combined detect + meta (1 blk)
__global__ __launch_bounds__(256) void detect_meta_kernel(
    const void* __restrict__ x, const void* __restrict__ pm,
    int* __restrict__ meta) {
  __shared__ int cnt;
  __shared__ int bigfound;
  __shared__ int pc[kB];
  int tid = threadIdx.x;
  if (tid == 0) { cnt = 0; bigfound = 0; }
  if (tid < kB) pc[tid] = 0;
  __syncthreads();
  // dtype: bf16 N(0,1) data never has exp field >= 0x90; fp32-as-u16 does.
  const unsigned short* u = (const unsigned short*)x;
  int c = 0;
  for (int i = tid; i < 1024; i += 256) {
    int e = (u[i] >> 7) & 0xFF;
    if (e >= 0x90) c++;
  }
  if (c) atomicAdd(&cnt, c);
  // pm layout: any word outside {0,1} => byte-bool layout.
  const unsigned int* wp = (const unsigned int*)pm;
  int f = 0;
  for (int i = tid; i < 2048; i += 256)
    if (wp[i] & 0xFFFFFFFEu) f = 1;
  if (f) atomicOr(&bigfound, 1);
  __syncthreads();
  int flag = bigfound ? 0 : 1;
  for (int i = tid; i < kTok; i += 256)
    if (is_pad(pm, flag, i)) atomicAdd(&pc[i >> 10], 1);
  __syncthreads();
  if (tid == 0) {
    meta[0] = flag;
    meta[9] = (cnt > 64) ? 1 : 0;
  }
  if (tid < kB) {
    int vl = kS - pc[tid];
    if (vl < 1) vl = 1;
    meta[1 + tid] = vl;
  }
}

// ------------------------------------- combined ingest (one launch, all)
struct CvtJob { const void* src; bf16* hi; bf16* lo; int nblk; };
struct CvtJobs { CvtJob j[13]; };
struct CvtFJob { const void* src; float* dst; int n; };
struct CvtFJobs { CvtFJob j[16]; };
__global__ __launch_bounds__(256) void cvt_all_kernel(
    CvtJobs jobs, CvtFJobs fjobs, int totblk, const int* __restrict__ meta) {
  int fp = meta[9];
  int b = blockIdx.x;
  if (b >= totblk) {  // tail block: all small fp32 conversions
#pragma unroll 1
    for (int ji = 0; ji < 16; ji++) {
      CvtFJob J = fjobs.j[ji];
      for (int i = threadIdx.x; i < J.n; i += 256)
        J.dst[i] = fp ? ((const float*)J.src)[i]
                      : __bfloat162float(((const bf16*)J.src)[i]);
    }
    return;
  }
  int ji = 0;
  while (b >= jobs.j[ji].nblk) { b -= jobs.j[ji].nblk; ji++; }
  CvtJob J = jobs.j[ji];
  int i = b * 1024 + threadIdx.x * 4;
  float v[4];
  if (fp) {
    float4 f = ((const float4*)J.src)[i >> 2];
    v[0] = f.x; v[1] = f.y; v[2] = f.z; v[3] = f.w;
  } else {
    uint2 u = *(const uint2*)((const bf16*)J.src + i);
    const bf16* h = (const bf16*)&u;
#pragma unroll
    for (int e = 0; e < 4; e++) v[e] = __bfloat162float(h[e]);
  }
  uint2 uh;
  bf16* hh = (bf16*)&uh;
#pragma unroll
  for (int e = 0; e < 4; e++) hh[e] = __float2bfloat16(v[e]);
  *(uint2*)(J.hi + i) = uh;
  if (J.lo) {
    uint2 ul;
    bf16* hl = (bf16*)&ul;
#pragma unroll
    for (int e = 0; e < 4; e++)
      hl[e] = __float2bfloat16(v[e] - __bfloat162float(hh[e]));
    *(uint2*)(J.lo + i) = ul;
  }
}

// ------------------------------------------------------------- GEMM core
// C[M,N] = act(A[M,K] @ W[N,K]^T + bias). R7-proven structure: 2-buffer LDS,
// global_load_lds dwordx4 staging, full drain before each barrier.
// LDS rows UNPADDED 64B; chunk slot sigma of row r holds global chunk
// sigma ^ ((r>>1)&3) -> conflict-free ds_read_b128. smem passed by pointer
// so merged job-table kernels share one allocation.
// mfma operands swapped: lane's 4 acc regs = 4 consecutive N-cols.
static constexpr int BK = 32;

template <int BM, int BN, int ACT, typename OUTT>
__device__ __forceinline__ void gemm_core(bf16* smem, const bf16* A,
                                          const bf16* W, const float* bias,
                                          OUTT* C, int N, int K, int m0,
                                          int n0) {
  constexpr int WR = (BM == 128 && BN == 128) ? 4 : 2;
  constexpr int WC = 4;
  bf16* As[2] = {smem, smem + BM * BK};
  bf16* Bs[2] = {smem + 2 * BM * BK, smem + 2 * BM * BK + BN * BK};
  const int tid = threadIdx.x;
  const int lane = tid & 63;
  const int wid = tid >> 6;
  int wm, wn;
  if constexpr (BM == 128 && BN == 128) {
    wm = (wid >> 1) * 64; wn = (wid & 1) * 64;
  } else {  // 128x64
    wm = wid * 32; wn = 0;
  }

  auto stage = [&](int buf, int kt) {
#pragma unroll
    for (int c = 0; c < BM / 64; c++) {
      int seg = c * 64 + wid * 16;
      int row = seg + (lane >> 2);
      int ch = (lane & 3) ^ ((row >> 1) & 3);
      dma16(&A[(size_t)(m0 + row) * K + kt + ch * 8], &As[buf][seg * BK]);
    }
#pragma unroll
    for (int c = 0; c < BN / 64; c++) {
      int seg = c * 64 + wid * 16;
      int row = seg + (lane >> 2);
      int ch = (lane & 3) ^ ((row >> 1) & 3);
      dma16(&W[(size_t)(n0 + row) * K + kt + ch * 8], &Bs[buf][seg * BK]);
    }
  };

  floatx4 acc[WR][WC];
#pragma unroll
  for (int i = 0; i < WR; i++)
#pragma unroll
    for (int j = 0; j < WC; j++) acc[i][j] = (floatx4)0.0f;

  stage(0, 0);
  drain_all();
  __syncthreads();
  const int niter = K / BK;
  for (int k = 0; k < niter; k++) {
    const int cur = k & 1;
    if (k + 1 < niter) stage(cur ^ 1, (k + 1) * BK);  // async, in flight
    const int kb = lane >> 4;
    short8 af[WR], bfr[WC];
#pragma unroll
    for (int i = 0; i < WR; i++) {
      int r = wm + i * 16 + (lane & 15);
      af[i] = *(const short8*)(&As[cur][r * BK + ((kb ^ ((r >> 1) & 3)) << 3)]);
    }
#pragma unroll
    for (int j = 0; j < WC; j++) {
      int r = wn + j * 16 + (lane & 15);
      bfr[j] = *(const short8*)(&Bs[cur][r * BK + ((kb ^ ((r >> 1) & 3)) << 3)]);
    }
#pragma unroll
    for (int i = 0; i < WR; i++)
#pragma unroll
      for (int j = 0; j < WC; j++)
        acc[i][j] = __builtin_amdgcn_mfma_f32_16x16x32_bf16(bfr[j], af[i],
                                                            acc[i][j], 0, 0, 0);
    drain_all();
    __syncthreads();
  }

#pragma unroll
  for (int i = 0; i < WR; i++) {
    int row = m0 + wm + i * 16 + (lane & 15);
#pragma unroll
    for (int j = 0; j < WC; j++) {
      int col = n0 + wn + j * 16 + ((lane >> 4) << 2);
      float bv[4] = {0.f, 0.f, 0.f, 0.f};
      if (bias) {
        float4 b4 = *(const float4*)&bias[col];
        bv[0] = b4.x; bv[1] = b4.y; bv[2] = b4.z; bv[3] = b4.w;
      }
      float v[4];
#pragma unroll
      for (int r = 0; r < 4; r++) {
        v[r] = acc[i][j][r] + bv[r];
        if (ACT == 1) v[r] = fast_gelu(v[r]);
        else if (ACT == 2) v[r] = 1.0f / (1.0f + __expf(-v[r]));
      }
      size_t idx = (size_t)row * N + col;
      if constexpr (std::is_same<OUTT, float>::value) {
        *(float4*)&C[idx] = make_float4(v[0], v[1], v[2], v[3]);
      } else {
        uint2 u;
        bf16* h = (bf16*)&u;
#pragma unroll
        for (int r = 0; r < 4; r++) h[r] = __float2bfloat16(v[r]);
        *(uint2*)&C[idx] = u;
      }
    }
  }
}

// ---------------------------------------------- fused hi/lo triple core
// acc = Ah@Wh^T (+ Ah@Wl^T if fp) (+ Al@Wh^T if fp||ALWAYS_AL) + bias.
// Offset branch (index-critical). Single-buffered stage->drain->sync.
// SPLIT: epilogue applies exact erff-gelu and writes bf16 hi/lo pair.
template <int BM, int BN, bool SPLIT, bool ALWAYS_AL>
__device__ __forceinline__ void gemm3_core(
    bf16* smem, const bf16* Ah, const bf16* Al, const bf16* Wh,
    const bf16* Wl, const float* bias, const int* meta, float* Cf, bf16* Chi,
    bf16* Clo, int N, int K, int m0, int n0) {
  constexpr int WR = 2;
  constexpr int WC = (BM == 128) ? 4 : 2;
  bf16* Ash = smem;
  bf16* Asl = smem + BM * BK;
  bf16* Bsh = smem + 2 * BM * BK;
  bf16* Bsl = smem + 2 * BM * BK + BN * BK;
  const int fp = meta[9];
  const bool use_al = fp || ALWAYS_AL;
  const int tid = threadIdx.x;
  const int lane = tid & 63;
  const int wid = tid >> 6;
  int wm, wn;
  if constexpr (BM == 128) {
    wm = wid * 32; wn = 0;
  } else {
    wm = (wid >> 1) * 32; wn = (wid & 1) * 32;
  }

  floatx4 acc[WR][WC];
#pragma unroll
  for (int i = 0; i < WR; i++)
#pragma unroll
    for (int j = 0; j < WC; j++) acc[i][j] = (floatx4)0.0f;

  for (int kt = 0; kt < K; kt += BK) {
#pragma unroll
    for (int c = 0; c < BM / 64; c++) {
      int seg = c * 64 + wid * 16;
      int row = seg + (lane >> 2);
      int ch = (lane & 3) ^ ((row >> 1) & 3);
      size_t g = (size_t)(m0 + row) * K + kt + ch * 8;
      dma16(&Ah[g], &Ash[seg * BK]);
      if (use_al) dma16(&Al[g], &Asl[seg * BK]);
    }
#pragma unroll
    for (int c = 0; c < BN / 64; c++) {
      int seg = c * 64 + wid * 16;
      int row = seg + (lane >> 2);
      int ch = (lane & 3) ^ ((row >> 1) & 3);
      size_t g = (size_t)(n0 + row) * K + kt + ch * 8;
      dma16(&Wh[g], &Bsh[seg * BK]);
      if (fp) dma16(&Wl[g], &Bsl[seg * BK]);
    }
    drain_all();
    __syncthreads();
    const int kb = lane >> 4;
    short8 ah[WR], al[WR], bh[WC], bl[WC];
#pragma unroll
    for (int i = 0; i < WR; i++) {
      int r = wm + i * 16 + (lane & 15);
      int ro = r * BK + ((kb ^ ((r >> 1) & 3)) << 3);
      ah[i] = *(const short8*)(&Ash[ro]);
      if (use_al) al[i] = *(const short8*)(&Asl[ro]);
    }
#pragma unroll
    for (int j = 0; j < WC; j++) {
      int r = wn + j * 16 + (lane & 15);
      int ro = r * BK + ((kb ^ ((r >> 1) & 3)) << 3);
      bh[j] = *(const short8*)(&Bsh[ro]);
      if (fp) bl[j] = *(const short8*)(&Bsl[ro]);
    }
#pragma unroll
    for (int i = 0; i < WR; i++)
#pragma unroll
      for (int j = 0; j < WC; j++) {
        acc[i][j] = __builtin_amdgcn_mfma_f32_16x16x32_bf16(bh[j], ah[i],
                                                            acc[i][j], 0, 0, 0);
        if (fp)
          acc[i][j] = __builtin_amdgcn_mfma_f32_16x16x32_bf16(
              bl[j], ah[i], acc[i][j], 0, 0, 0);
        if (use_al)
          acc[i][j] = __builtin_amdgcn_mfma_f32_16x16x32_bf16(
              bh[j], al[i], acc[i][j], 0, 0, 0);
      }
    __syncthreads();
  }

#pragma unroll
  for (int i = 0; i < WR; i++) {
    int row = m0 + wm + i * 16 + (lane & 15);
#pragma unroll
    for (int j = 0; j < WC; j++) {
      int col = n0 + wn + j * 16 + ((lane >> 4) << 2);
      float4 b4 = *(const float4*)&bias[col];
      float bv[4] = {b4.x, b4.y, b4.z, b4.w};
      if constexpr (SPLIT) {
        uint2 uh, ul;
        bf16* hh = (bf16*)&uh;
        bf16* hl = (bf16*)&ul;
#pragma unroll
        for (int r = 0; r < 4; r++) {
          float v = acc[i][j][r] + bv[r];
          float g = 0.5f * v * (1.0f + erff(v * 0.70710678118654752f));
          bf16 hi = __float2bfloat16(g);
          hh[r] = hi;
          hl[r] = __float2bfloat16(g - __bfloat162float(hi));
        }
        *(uint2*)&Chi[(size_t)row * N + col] = uh;
        *(uint2*)&Clo[(size_t)row * N + col] = ul;
      } else {
        *(float4*)&Cf[(size_t)row * N + col] =
            make_float4(acc[i][j][0] + bv[0], acc[i][j][1] + bv[1],
                        acc[i][j][2] + bv[2], acc[i][j][3] + bv[3]);
      }
    }
  }
}

// ------------------------------------------------- plain GEMM wrappers
template <int BM, int BN, int ACT, typename OUTT>
__global__ __launch_bounds__(256) void gemm_bt(
    const bf16* __restrict__ A, const bf16* __restrict__ W,
    const float* __restrict__ bias, OUTT* __restrict__ C, int N, int K) {
  __shared__ bf16 smem[2 * (BM + BN) * BK];
  gemm_core<BM, BN, ACT, OUTT>(smem, A, W, bias, C, N, K, blockIdx.x * BM,
                               blockIdx.y * BN);
}

// two independent E*E GEMMs in one launch (mha_out + do_out)
__global__ __launch_bounds__(256) void gemm_pair(
    const bf16* __restrict__ A0, const bf16* __restrict__ W0,
    const float* __restrict__ b0, bf16* __restrict__ C0,
    const bf16* __restrict__ A1, const bf16* __restrict__ W1,
    const float* __restrict__ b1, bf16* __restrict__ C1, int N, int K) {
  __shared__ bf16 smem[2 * (128 + 64) * BK];
  int nb = N >> 6;
  bool s = (int)blockIdx.y >= nb;
  gemm_core<128, 64, 0, bf16>(smem, s ? A1 : A0, s ? W1 : W0, s ? b1 : b0,
                              s ? C1 : C0, N, K, blockIdx.x * 128,
                              (s ? (int)blockIdx.y - nb : (int)blockIdx.y) * 64);
}

// --------------------------- merged: qkv projection (N=3072) + o1 gemm3
// y in [0,24): qkv gemm. y in [24,32): o1 (N=512) hi/lo triple + gelu split.
__global__ __launch_bounds__(256) void qkv_o1_kernel(
    const bf16* __restrict__ x_hi, const bf16* __restrict__ x_lo,
    const bf16* __restrict__ wall, const float* __restrict__ ball,
    bf16* __restrict__ qkv_all, const bf16* __restrict__ o1h,
    const bf16* __restrict__ o1l, const float* __restrict__ o1b,
    const int* __restrict__ meta, bf16* __restrict__ h_hi,
    bf16* __restrict__ h_lo) {
  __shared__ bf16 smem[2 * 256 * BK];  // 32KB: max(gemm 32KB, gemm3 24KB)
  if ((int)blockIdx.y < 24) {
    gemm_core<128, 128, 0, bf16>(smem, x_hi, wall, ball, qkv_all, 3072, kE,
                                 blockIdx.x * 128, blockIdx.y * 128);
  } else {
    gemm3_core<128, 64, true, false>(smem, x_hi, x_lo, o1h, o1l, o1b, meta,
                                     nullptr, h_hi, h_lo, kE, kE,
                                     blockIdx.x * 128,
                                     ((int)blockIdx.y - 24) * 64);
  }
}

// ------------------------------------------------------- local attention
// qkv_all row stride 3072: [q 0:512 | k 512:1024 | v 1024:1536 | qd|kd|vd]
__device__ __forceinline__ void local_attn_body(const bf16* __restrict__ qkv,
                                                const void* __restrict__ pm,
                                                const int* __restrict__ meta,
                                                bf16* __restrict__ lo,
                                                int bid) {
  int lane = threadIdx.x & 63;
  int t = bid * 4 + (threadIdx.x >> 6);
  int b = t >> 10, s = t & 1023;
  int h = lane >> 3, sub = lane & 7;
  int flag = meta[0];
  float q[8];
  load8f(qkv + (size_t)t * 3072 + h * 64 + sub * 8, q);
  float sc[4];
  bool val[4];
#pragma unroll
  for (int w = 0; w < 4; w++) {
    int kp = s - 3 + w;
    bool v = (kp >= 0) && !is_pad(pm, flag, b * kS + kp);
    float d = 0.0f;
    if (v) {
      float kk[8];
      load8f(qkv + (size_t)(b * kS + kp) * 3072 + 512 + h * 64 + sub * 8, kk);
#pragma unroll
      for (int e = 0; e < 8; e++) d += q[e] * kk[e];
    }
    d += __shfl_xor(d, 1);
    d += __shfl_xor(d, 2);
    d += __shfl_xor(d, 4);
    sc[w] = v ? d / 8.0f : -INFINITY;
    val[w] = v;
  }
  float mx = fmaxf(fmaxf(sc[0], sc[1]), fmaxf(sc[2], sc[3]));
  float a[4] = {0.f, 0.f, 0.f, 0.f};
  if (mx != -INFINITY) {
    float ssum = 0.f;
#pragma unroll
    for (int w = 0; w < 4; w++) {
      float e = val[w] ? expf(sc[w] - mx) : 0.0f;
      a[w] = e;
      ssum += e;
    }
#pragma unroll
    for (int w = 0; w < 4; w++) a[w] /= ssum;
  }
  float o[8] = {0.f, 0.f, 0.f, 0.f, 0.f, 0.f, 0.f, 0.f};
#pragma unroll
  for (int w = 0; w < 4; w++) {
    if (val[w] && a[w] > 0.0f) {
      int kp = s - 3 + w;
      float vv[8];
      load8f(qkv + (size_t)(b * kS + kp) * 3072 + 1024 + h * 64 + sub * 8, vv);
#pragma unroll
      for (int e = 0; e < 8; e++) o[e] += a[w] * vv[e];
    }
  }
  store8b(lo + (size_t)t * kE + lane * 8, o);
}

// ---------------------- merged: local attention (2048) + o2 gemm3 (512)
__global__ __launch_bounds__(256) void local_o2_kernel(
    const bf16* __restrict__ qkv, const void* __restrict__ pm,
    const int* __restrict__ meta, bf16* __restrict__ lo_ctx,
    const bf16* __restrict__ h_hi, const bf16* __restrict__ h_lo,
    const bf16* __restrict__ o2h, const bf16* __restrict__ o2l,
    const float* __restrict__ o2b, float* __restrict__ rawf) {
  __shared__ bf16 smem[4 * 64 * BK];  // 16KB for the o2 gemm3<64,64>
  if ((int)blockIdx.x < 2048) {
    local_attn_body(qkv, pm, meta, lo_ctx, blockIdx.x);
  } else {
    int id = (int)blockIdx.x - 2048;  // 512 blocks: m 128 x n 4
    gemm3_core<64, 64, false, true>(smem, h_hi, h_lo, o2h, o2l, o2b, meta,
                                    rawf, nullptr, nullptr, 256, kE,
                                    (id >> 2) * 64, (id & 3) * 64);
  }
}

// ------------------- long attention with INLINE sampler (one wave/token)
// qkv_all: qd at +1536, kd at +2048, vd at +2560 (stride 3072).
__global__ __launch_bounds__(256) void long_attn_kernel(
    const bf16* __restrict__ qkv, const float* __restrict__ rawf,
    const void* __restrict__ pm, const int* __restrict__ meta,
    bf16* __restrict__ ctx) {
  int lane = threadIdx.x & 63;
  int bid = blockIdx.x;
  int sbid = (bid & 7) * 256 + (bid >> 3);  // XCD-contiguous token ranges
  int t = sbid * 4 + (threadIdx.x >> 6);
  int b = t >> 10, s = t & 1023;
  int flag = meta[0];
  int p = lane & 31;
  // ---- inline sampler (both wave halves compute identical values for p)
  float off = 0.0f;
#pragma unroll
  for (int h = 0; h < kH; h++) off += tanhf(rawf[(size_t)t * 256 + h * kP + p]);
  double anchor = 0.1 + 0.8 * (double)p / 31.0;
  double sampled = anchor * (double)s + (double)off;
  double lov = fmax(0.0, (double)s - 256.0);
  sampled = fmin(fmax(sampled, lov), (double)s);
  int vlen = meta[1 + b];
  sampled = fmin(sampled, (double)(vlen - 1));
  int spv = (int)rint(sampled);  // half-to-even, matches np.round
  bool inv = is_pad(pm, flag, b * kS + spv) || (spv > s) ||
             (spv >= max(0, s - 3));
  int row_abs = b * kS + spv;
  // ---- QK: per-sample coalesced K-row load + butterfly reduce
  float q[8];
  load8f(qkv + (size_t)t * 3072 + 1536 + lane * 8, q);
  float sc_mine = 0.0f;
#pragma unroll 4
  for (int pp = 0; pp < 32; pp++) {
    int row = __shfl(row_abs, pp);
    float kk[8];
    load8f(qkv + (size_t)row * 3072 + 2048 + lane * 8, kk);
    float d = 0.0f;
#pragma unroll
    for (int e = 0; e < 8; e++) d += q[e] * kk[e];
#pragma unroll
    for (int m = 1; m < 64; m <<= 1) d += __shfl_xor(d, m);
    if (p == pp) sc_mine = d;
  }
  float sc = inv ? -INFINITY : sc_mine / 22.627416997969522f;  // sqrt(512)
  float mx = sc;
#pragma unroll
  for (int m = 1; m < 32; m <<= 1) mx = fmaxf(mx, __shfl_xor(mx, m));
  float e = (inv || mx == -INFINITY) ? 0.0f : expf(sc - mx);
  float ssum = e;
#pragma unroll
  for (int m = 1; m < 32; m <<= 1) ssum += __shfl_xor(ssum, m);
  float a = (ssum > 0.0f) ? e / ssum : 0.0f;
  float o[8] = {0.f, 0.f, 0.f, 0.f, 0.f, 0.f, 0.f, 0.f};
#pragma unroll 4
  for (int pp = 0; pp < 32; pp++) {
    float ap = __shfl(a, pp);
    int row = __shfl(row_abs, pp);
    if (ap != 0.0f) {
      float vv[8];
      load8f(qkv + (size_t)row * 3072 + 2560 + lane * 8, vv);
#pragma unroll
      for (int e2 = 0; e2 < 8; e2++) o[e2] += ap * vv[e2];
    }
  }
  store8b(ctx + (size_t)t * kE + lane * 8, o);
}

// gate1: A is virtual concat [x | local_out | long_out] (K=1536), gelu act.
__global__ __launch_bounds__(256) void gemm_gate1(
    const bf16* __restrict__ x, const bf16* __restrict__ lo,
    const bf16* __restrict__ lg, const bf16* __restrict__ W,
    const float* __restrict__ bias, bf16* __restrict__ C) {
  constexpr int BM = 128, BN = 64, WR = 2, WC = 4;
  constexpr int N = 512, K = 1536;
  __shared__ bf16 As[2][BM * BK];
  __shared__ bf16 Bs[2][BN * BK];
  const int tid = threadIdx.x;
  const int lane = tid & 63;
  const int wid = tid >> 6;
  const int wm = wid * 32, wn = 0;
  const int m0 = blockIdx.x * BM, n0 = blockIdx.y * BN;

  auto stage = [&](int buf, int kt) {
    const bf16* src = (kt < 512) ? x : (kt < 1024) ? lo : lg;
    int kk = kt & 511;
#pragma unroll
    for (int c = 0; c < 2; c++) {
      int seg = c * 64 + wid * 16;
      int row = seg + (lane >> 2);
      int ch = (lane & 3) ^ ((row >> 1) & 3);
      dma16(&src[(size_t)(m0 + row) * 512 + kk + ch * 8], &As[buf][seg * BK]);
    }
    {
      int seg = wid * 16;
      int row = seg + (lane >> 2);
      int ch = (lane & 3) ^ ((row >> 1) & 3);
      dma16(&W[(size_t)(n0 + row) * K + kt + ch * 8], &Bs[buf][seg * BK]);
    }
  };

  floatx4 acc[WR][WC];
#pragma unroll
  for (int i = 0; i < WR; i++)
#pragma unroll
    for (int j = 0; j < WC; j++) acc[i][j] = (floatx4)0.0f;

  stage(0, 0);
  drain_all();
  __syncthreads();
  const int niter = K / BK;
  for (int k = 0; k < niter; k++) {
    const int cur = k & 1;
    if (k + 1 < niter) stage(cur ^ 1, (k + 1) * BK);
    const int kb = lane >> 4;
    short8 af[WR], bfr[WC];
#pragma unroll
    for (int i = 0; i < WR; i++) {
      int r = wm + i * 16 + (lane & 15);
      af[i] = *(const short8*)(&As[cur][r * BK + ((kb ^ ((r >> 1) & 3)) << 3)]);
    }
#pragma unroll
    for (int j = 0; j < WC; j++) {
      int r = wn + j * 16 + (lane & 15);
      bfr[j] = *(const short8*)(&Bs[cur][r * BK + ((kb ^ ((r >> 1) & 3)) << 3)]);
    }
#pragma unroll
    for (int i = 0; i < WR; i++)
#pragma unroll
      for (int j = 0; j < WC; j++)
        acc[i][j] = __builtin_amdgcn_mfma_f32_16x16x32_bf16(bfr[j], af[i],
                                                            acc[i][j], 0, 0, 0);
    drain_all();
    __syncthreads();
  }

#pragma unroll
  for (int i = 0; i < WR; i++) {
    int row = m0 + wm + i * 16 + (lane & 15);
#pragma unroll
    for (int j = 0; j < WC; j++) {
      int col = n0 + wn + j * 16 + ((lane >> 4) << 2);
      float4 b4 = *(const float4*)&bias[col];
      float bv[4] = {b4.x, b4.y, b4.z, b4.w};
      uint2 u;
      bf16* h = (bf16*)&u;
#pragma unroll
      for (int r = 0; r < 4; r++)
        h[r] = __float2bfloat16(fast_gelu(acc[i][j][r] + bv[r]));
      *(uint2*)&C[(size_t)row * N + col] = u;
    }
  }
}

// ------------------------------------------------------------------- LN1
__global__ __launch_bounds__(256) void ln1_kernel(
    const void* __restrict__ xin, const int* __restrict__ meta,
    const bf16* __restrict__ lo, const bf16* __restrict__ lg,
    const bf16* __restrict__ g, const float* __restrict__ gamma,
    const float* __restrict__ beta, bf16* __restrict__ x1b,
    float* __restrict__ x1f) {
  int lane = threadIdx.x & 63;
  int t = blockIdx.x * 4 + (threadIdx.x >> 6);
  size_t base = (size_t)t * kE + lane * 8;
  float xv[8], lov[8], lgv[8], gv[8], h[8];
  if (meta[9]) {
    const float4* xf = (const float4*)((const float*)xin + base);
    float4 a = xf[0], b2 = xf[1];
    xv[0] = a.x; xv[1] = a.y; xv[2] = a.z; xv[3] = a.w;
    xv[4] = b2.x; xv[5] = b2.y; xv[6] = b2.z; xv[7] = b2.w;
  } else {
    load8f((const bf16*)xin + base, xv);
  }
  load8f(lo + base, lov);
  load8f(lg + base, lgv);
  load8f(g + base, gv);
  float s1 = 0.f, s2 = 0.f;
#pragma unroll
  for (int e = 0; e < 8; e++) {
    h[e] = xv[e] + gv[e] * lov[e] + (1.0f - gv[e]) * lgv[e];
    s1 += h[e];
    s2 += h[e] * h[e];
  }
#pragma unroll
  for (int m = 1; m < 64; m <<= 1) {
    s1 += __shfl_xor(s1, m);
    s2 += __shfl_xor(s2, m);
  }
  float mean = s1 * (1.0f / kE);
  float var = s2 * (1.0f / kE) - mean * mean;
  float rstd = 1.0f / sqrtf(var + 1e-5f);
  float y[8];
#pragma unroll
  for (int e = 0; e < 8; e++)
    y[e] = (h[e] - mean) * rstd * gamma[lane * 8 + e] + beta[lane * 8 + e];
  store8b(x1b + base, y);
#pragma unroll
  for (int e = 0; e < 8; e++) x1f[base + e] = y[e];
}

// ------------------------------------------------------------------- LN2
__global__ __launch_bounds__(256) void ln2_kernel(
    const float* __restrict__ x1f, const float* __restrict__ ff,
    const float* __restrict__ gamma, const float* __restrict__ beta,
    const int* __restrict__ meta, void* __restrict__ out) {
  int lane = threadIdx.x & 63;
  int t = blockIdx.x * 4 + (threadIdx.x >> 6);
  size_t base = (size_t)t * kE + lane * 8;
  float h[8];
  float s1 = 0.f, s2 = 0.f;
#pragma unroll
  for (int e = 0; e < 8; e++) {
    h[e] = x1f[base + e] + ff[base + e];
    s1 += h[e];
    s2 += h[e] * h[e];
  }
#pragma unroll
  for (int m = 1; m < 64; m <<= 1) {
    s1 += __shfl_xor(s1, m);
    s2 += __shfl_xor(s2, m);
  }
  float mean = s1 * (1.0f / kE);
  float var = s2 * (1.0f / kE) - mean * mean;
  float rstd = 1.0f / sqrtf(var + 1e-5f);
  float y[8];
#pragma unroll
  for (int e = 0; e < 8; e++)
    y[e] = (h[e] - mean) * rstd * gamma[lane * 8 + e] + beta[lane * 8 + e];
  if (meta[9]) {
    float* of = (float*)out + base;
    ((float4*)of)[0] = make_float4(y[0], y[1], y[2], y[3]);
    ((float4*)of)[1] = make_float4(y[4], y[5], y[6], y[7]);
  } else {
    store8b((bf16*)out + base, y);
  }
}

// ------------------------------------------------------------------ launch
extern "C" void kernel_launch(void* const* d_in, const int* in_sizes, int n_in,
                              void* d_out, int out_size, void* d_ws,
                              size_t ws_size, hipStream_t stream) {
  const void* x = d_in[0];
  const void* pm = d_in[1];

  char* w = (char*)d_ws;
  auto alloc = [&](size_t bytes) {
    char* p = w;
    w += (bytes + 255) & ~(size_t)255;
    return p;
  };
  bf16* qkv_all = (bf16*)alloc((size_t)kTok * 3072 * 2);  // recycled later
  bf16* lo_ctx = (bf16*)alloc((size_t)kTok * kE * 2);
  bf16* ctx2 = (bf16*)alloc((size_t)kTok * kE * 2);
  bf16* local_out = (bf16*)alloc((size_t)kTok * kE * 2);
  bf16* long_out = (bf16*)alloc((size_t)kTok * kE * 2);
  bf16* hbuf = (bf16*)alloc((size_t)kTok * kE * 2);    // h_hi / gate hidden
  bf16* gbuf = (bf16*)alloc((size_t)kTok * kE * 2);    // gate out
  bf16* x1b = (bf16*)alloc((size_t)kTok * kE * 2);     // h_lo / x1 bf16
  float* x1f = (float*)alloc((size_t)kTok * kE * 4);   // x1 fp32
  float* rawf = (float*)alloc((size_t)kTok * 256 * 4);
  int* meta = (int*)alloc(256);
  bf16* x_hi = (bf16*)alloc((size_t)kTok * kE * 2);
  bf16* x_lo = (bf16*)alloc((size_t)kTok * kE * 2);
  bf16* wall = (bf16*)alloc((size_t)3072 * 512 * 2);  // ip|dq|dk|dv weights
  bf16* mow = (bf16*)alloc(512 * 512 * 2);
  bf16* dow = (bf16*)alloc(512 * 512 * 2);
  bf16* o1h = (bf16*)alloc(512 * 512 * 2);
  bf16* o1l = (bf16*)alloc(512 * 512 * 2);
  bf16* o2h = (bf16*)alloc(256 * 512 * 2);
  bf16* o2l = (bf16*)alloc(256 * 512 * 2);
  bf16* g1w = (bf16*)alloc(512 * 1536 * 2);
  bf16* g2w = (bf16*)alloc(512 * 512 * 2);
  bf16* f1w = (bf16*)alloc((size_t)2048 * 512 * 2);
  bf16* f2w = (bf16*)alloc((size_t)512 * 2048 * 2);
  float* ball = (float*)alloc(3072 * 4);
  float* mob = (float*)alloc(512 * 4);
  float* dob = (float*)alloc(512 * 4);
  float* o1b = (float*)alloc(512 * 4);
  float* o2b = (float*)alloc(256 * 4);
  float* g1b = (float*)alloc(512 * 4);
  float* g2b = (float*)alloc(512 * 4);
  float* n1g = (float*)alloc(512 * 4);
  float* n1bt = (float*)alloc(512 * 4);
  float* n2g = (float*)alloc(512 * 4);
  float* n2bt = (float*)alloc(512 * 4);
  float* f1b = (float*)alloc(2048 * 4);
  float* f2b = (float*)alloc(512 * 4);

  bf16* h_hi = hbuf;
  bf16* h_lo = x1b;
  float* f_f32 = (float*)qkv_all;                                 // 16.8MB
  bf16* ffn_h = (bf16*)((char*)qkv_all + (size_t)kTok * kE * 4);  // 33.5MB

  dim3 blk(256);
  detect_meta_kernel<<<1, blk, 0, stream>>>(x, pm, meta);

  // ---- combined ingest (one launch)
  CvtJobs J;
  auto job = [](const void* s, bf16* hi, bf16* lo, int n) {
    CvtJob j; j.src = s; j.hi = hi; j.lo = lo; j.nblk = n >> 10; return j;
  };
  J.j[0] = job(d_in[0], x_hi, x_lo, kTok * kE);
  J.j[1] = job(d_in[2], wall, nullptr, 1536 * 512);
  J.j[2] = job(d_in[6], wall + (size_t)1536 * 512, nullptr, 512 * 512);
  J.j[3] = job(d_in[8], wall + (size_t)2048 * 512, nullptr, 512 * 512);
  J.j[4] = job(d_in[10], wall + (size_t)2560 * 512, nullptr, 512 * 512);
  J.j[5] = job(d_in[4], mow, nullptr, 512 * 512);
  J.j[6] = job(d_in[12], dow, nullptr, 512 * 512);
  J.j[7] = job(d_in[14], o1h, o1l, 512 * 512);
  J.j[8] = job(d_in[16], o2h, o2l, 256 * 512);
  J.j[9] = job(d_in[18], g1w, nullptr, 512 * 1536);
  J.j[10] = job(d_in[20], g2w, nullptr, 512 * 512);
  J.j[11] = job(d_in[26], f1w, nullptr, 2048 * 512);
  J.j[12] = job(d_in[28], f2w, nullptr, 512 * 2048);
  int totblk = 0;
  for (int i = 0; i < 13; i++) totblk += J.j[i].nblk;

  CvtFJobs JF;
  auto fjob = [](const void* s, float* d, int n) {
    CvtFJob j; j.src = s; j.dst = d; j.n = n; return j;
  };
  JF.j[0] = fjob(d_in[3], ball, 1536);
  JF.j[1] = fjob(d_in[7], ball + 1536, 512);
  JF.j[2] = fjob(d_in[9], ball + 2048, 512);
  JF.j[3] = fjob(d_in[11], ball + 2560, 512);
  JF.j[4] = fjob(d_in[5], mob, 512);
  JF.j[5] = fjob(d_in[13], dob, 512);
  JF.j[6] = fjob(d_in[15], o1b, 512);
  JF.j[7] = fjob(d_in[17], o2b, 256);
  JF.j[8] = fjob(d_in[19], g1b, 512);
  JF.j[9] = fjob(d_in[21], g2b, 512);
  JF.j[10] = fjob(d_in[22], n1g, 512);
  JF.j[11] = fjob(d_in[23], n1bt, 512);
  JF.j[12] = fjob(d_in[24], n2g, 512);
  JF.j[13] = fjob(d_in[25], n2bt, 512);
  JF.j[14] = fjob(d_in[27], f1b, 2048);
  JF.j[15] = fjob(d_in[29], f2b, 512);
  cvt_all_kernel<<<totblk + 1, blk, 0, stream>>>(J, JF, totblk, meta);

  // ---- merged qkv(N=3072) + o1 offset triple (one launch)
  qkv_o1_kernel<<<dim3(64, 32), blk, 0, stream>>>(
      x_hi, x_lo, wall, ball, qkv_all, o1h, o1l, o1b, meta, h_hi, h_lo);
  // ---- merged local attention + o2 offset triple (one launch)
  local_o2_kernel<<<2560, blk, 0, stream>>>(qkv_all, pm, meta, lo_ctx, h_hi,
                                            h_lo, o2h, o2l, o2b, rawf);
  // ---- long attention with inline sampler
  long_attn_kernel<<<2048, blk, 0, stream>>>(qkv_all, rawf, pm, meta, ctx2);

  // ---- both attention output projections in one launch
  gemm_pair<<<dim3(64, 16), blk, 0, stream>>>(lo_ctx, mow, mob, local_out,
                                              ctx2, dow, dob, long_out, kE, kE);

  // ---- gate (virtual concat in gate1 staging)
  gemm_gate1<<<dim3(64, 8), blk, 0, stream>>>(x_hi, local_out, long_out, g1w,
                                              g1b, hbuf);
  gemm_bt<128, 64, 2, bf16><<<dim3(64, 8), blk, 0, stream>>>(
      hbuf, g2w, g2b, gbuf, kE, kE);

  // ---- fuse + LN1 + FFN + LN2
  ln1_kernel<<<2048, blk, 0, stream>>>(x, meta, local_out, long_out, gbuf, n1g,
                                       n1bt, x1b, x1f);
  gemm_bt<128, 128, 1, bf16><<<dim3(64, 16), blk, 0, stream>>>(
      x1b, f1w, f1b, ffn_h, kHid, kE);
  gemm_bt<128, 64, 0, float><<<dim3(64, 8), blk, 0, stream>>>(
      ffn_h, f2w, f2b, f_f32, kE, kHid);
  ln2_kernel<<<2048, blk, 0, stream>>>(x1f, f_f32, n2g, n2bt, meta, d_out);
}

// Round 10
// 477.397 us; speedup vs baseline: 1.0546x; 1.0546x over previous
//
#include <hip/hip_runtime.h>
#include <hip/hip_bf16.h>
#include <type_traits>

typedef __hip_bfloat16 bf16;
typedef __attribute__((ext_vector_type(8))) short short8;
typedef __attribute__((ext_vector_type(4))) float floatx4;

static constexpr int kB = 8;
static constexpr int kS = 1024;
static constexpr int kE = 512;
static constexpr int kH = 8;
static constexpr int kP = 32;
static constexpr int kTok = kB * kS;   // 8192
static constexpr int kHid = 2048;

// meta layout: [0]=pm int32 flag, [1..8]=valid_len, [9]=inputs-are-fp32 flag
// ---------------------------------------------------------------- helpers
__device__ __forceinline__ void load8f(const bf16* p, float* f) {
  uint4 u = *(const uint4*)p;
  const bf16* h = (const bf16*)&u;
#pragma unroll
  for (int e = 0; e < 8; e++) f[e] = __bfloat162float(h[e]);
}
__device__ __forceinline__ void store8b(bf16* p, const float* f) {
  uint4 u;
  bf16* h = (bf16*)&u;
#pragma unroll
  for (int e = 0; e < 8; e++) h[e] = __float2bfloat16(f[e]);
  *(uint4*)p = u;
}
__device__ __forceinline__ bool is_pad(const void* pm, int flag, int idx) {
  return flag ? (((const int*)pm)[idx] != 0)
              : (((const unsigned char*)pm)[idx] != 0);
}
__device__ __forceinline__ float fast_gelu(float x) {
  float u = x * (0.7978845608f + 0.044714998f * x * x);
  float e = __expf(2.0f * u);
  float t = 1.0f - 2.0f / (e + 1.0f);
  return 0.5f * x * (1.0f + t);
}
// async global->LDS 16B DMA. dest = wave-uniform lds base + lane*16.
__device__ __forceinline__ void dma16(const bf16* g, bf16* l) {
  __builtin_amdgcn_global_load_lds(
      (const __attribute__((address_space(1))) unsigned int*)g,
      (__attribute__((address_space(3))) unsigned int*)l, 16, 0, 0);
}
// Explicit full drain (vmcnt/lgkmcnt/expcnt = 0). REQUIRED before barriers
// that hand a DMA-written LDS buffer to other waves (R6 race: global_load_lds
// has no dest VGPR, compiler waitcnt pass misses the dependence).
__device__ __forceinline__ void drain_all() { __builtin_amdgcn_s_waitcnt(0); }

// ----------------------------------------- combined detect + meta (1 blk)
__global__ __launch_bounds__(256) void detect_meta_kernel(
    const void* __restrict__ x, const void* __restrict__ pm,
    int* __restrict__ meta) {
  __shared__ int cnt;
  __shared__ int bigfound;
  __shared__ int pc[kB];
  int tid = threadIdx.x;
  if (tid == 0) { cnt = 0; bigfound = 0; }
  if (tid < kB) pc[tid] = 0;
  __syncthreads();
  // dtype: bf16 N(0,1) data never has exp field >= 0x90; fp32-as-u16 does.
  const unsigned short* u = (const unsigned short*)x;
  int c = 0;
  for (int i = tid; i < 1024; i += 256) {
    int e = (u[i] >> 7) & 0xFF;
    if (e >= 0x90) c++;
  }
  if (c) atomicAdd(&cnt, c);
  // pm layout: any word outside {0,1} => byte-bool layout.
  const unsigned int* wp = (const unsigned int*)pm;
  int f = 0;
  for (int i = tid; i < 2048; i += 256)
    if (wp[i] & 0xFFFFFFFEu) f = 1;
  if (f) atomicOr(&bigfound, 1);
  __syncthreads();
  int flag = bigfound ? 0 : 1;
  for (int i = tid; i < kTok; i += 256)
    if (is_pad(pm, flag, i)) atomicAdd(&pc[i >> 10], 1);
  __syncthreads();
  if (tid == 0) {
    meta[0] = flag;
    meta[9] = (cnt > 64) ? 1 : 0;
  }
  if (tid < kB) {
    int vl = kS - pc[tid];
    if (vl < 1) vl = 1;
    meta[1 + tid] = vl;
  }
}

// ------------------------------------- combined ingest (one launch, all)
// bf16 mode (meta[9]==0): hi-copies are bitwise identity and every consumer
// selects the RAW pointer instead -> all 13 jobs early-exit; only the fp32
// bias conversions (tail block) run. fp32 mode: full conversion as before.
struct CvtJob { const void* src; bf16* hi; bf16* lo; int nblk; };
struct CvtJobs { CvtJob j[13]; };
struct CvtFJob { const void* src; float* dst; int n; };
struct CvtFJobs { CvtFJob j[16]; };
__global__ __launch_bounds__(256) void cvt_all_kernel(
    CvtJobs jobs, CvtFJobs fjobs, int totblk, const int* __restrict__ meta) {
  int fp = meta[9];
  int b = blockIdx.x;
  if (b >= totblk) {  // tail block: all small fp32 conversions
#pragma unroll 1
    for (int ji = 0; ji < 16; ji++) {
      CvtFJob J = fjobs.j[ji];
      for (int i = threadIdx.x; i < J.n; i += 256)
        J.dst[i] = fp ? ((const float*)J.src)[i]
                      : __bfloat162float(((const bf16*)J.src)[i]);
    }
    return;
  }
  if (!fp) return;  // bf16 passthrough mode: nothing to materialize
  int ji = 0;
  while (b >= jobs.j[ji].nblk) { b -= jobs.j[ji].nblk; ji++; }
  CvtJob J = jobs.j[ji];
  int i = b * 1024 + threadIdx.x * 4;
  float4 f = ((const float4*)J.src)[i >> 2];
  float v[4] = {f.x, f.y, f.z, f.w};
  uint2 uh;
  bf16* hh = (bf16*)&uh;
#pragma unroll
  for (int e = 0; e < 4; e++) hh[e] = __float2bfloat16(v[e]);
  *(uint2*)(J.hi + i) = uh;
  if (J.lo) {
    uint2 ul;
    bf16* hl = (bf16*)&ul;
#pragma unroll
    for (int e = 0; e < 4; e++)
      hl[e] = __float2bfloat16(v[e] - __bfloat162float(hh[e]));
    *(uint2*)(J.lo + i) = ul;
  }
}

// ------------------------------------------------------------- GEMM core
// C[M,N] = act(A[M,K] @ W[N,K]^T + bias). R7-proven structure: 2-buffer LDS,
// global_load_lds dwordx4 staging, full drain before each barrier.
// LDS rows UNPADDED 64B; chunk slot sigma of row r holds global chunk
// sigma ^ ((r>>1)&3) -> conflict-free ds_read_b128.
// n0w = W row offset (differs from C col offset n0 for segmented weights).
// mfma operands swapped: lane's 4 acc regs = 4 consecutive N-cols.
static constexpr int BK = 32;

template <int BM, int BN, int ACT, typename OUTT>
__device__ __forceinline__ void gemm_core(bf16* smem, const bf16* A,
                                          const bf16* W, const float* bias,
                                          OUTT* C, int N, int K, int m0,
                                          int n0, int n0w) {
  constexpr int WR = (BM == 128 && BN == 128) ? 4 : 2;
  constexpr int WC = 4;
  bf16* As[2] = {smem, smem + BM * BK};
  bf16* Bs[2] = {smem + 2 * BM * BK, smem + 2 * BM * BK + BN * BK};
  const int tid = threadIdx.x;
  const int lane = tid & 63;
  const int wid = tid >> 6;
  int wm, wn;
  if constexpr (BM == 128 && BN == 128) {
    wm = (wid >> 1) * 64; wn = (wid & 1) * 64;
  } else {  // 128x64
    wm = wid * 32; wn = 0;
  }

  auto stage = [&](int buf, int kt) {
#pragma unroll
    for (int c = 0; c < BM / 64; c++) {
      int seg = c * 64 + wid * 16;
      int row = seg + (lane >> 2);
      int ch = (lane & 3) ^ ((row >> 1) & 3);
      dma16(&A[(size_t)(m0 + row) * K + kt + ch * 8], &As[buf][seg * BK]);
    }
#pragma unroll
    for (int c = 0; c < BN / 64; c++) {
      int seg = c * 64 + wid * 16;
      int row = seg + (lane >> 2);
      int ch = (lane & 3) ^ ((row >> 1) & 3);
      dma16(&W[(size_t)(n0w + row) * K + kt + ch * 8], &Bs[buf][seg * BK]);
    }
  };

  floatx4 acc[WR][WC];
#pragma unroll
  for (int i = 0; i < WR; i++)
#pragma unroll
    for (int j = 0; j < WC; j++) acc[i][j] = (floatx4)0.0f;

  stage(0, 0);
  drain_all();
  __syncthreads();
  const int niter = K / BK;
  for (int k = 0; k < niter; k++) {
    const int cur = k & 1;
    if (k + 1 < niter) stage(cur ^ 1, (k + 1) * BK);  // async, in flight
    const int kb = lane >> 4;
    short8 af[WR], bfr[WC];
#pragma unroll
    for (int i = 0; i < WR; i++) {
      int r = wm + i * 16 + (lane & 15);
      af[i] = *(const short8*)(&As[cur][r * BK + ((kb ^ ((r >> 1) & 3)) << 3)]);
    }
#pragma unroll
    for (int j = 0; j < WC; j++) {
      int r = wn + j * 16 + (lane & 15);
      bfr[j] = *(const short8*)(&Bs[cur][r * BK + ((kb ^ ((r >> 1) & 3)) << 3)]);
    }
#pragma unroll
    for (int i = 0; i < WR; i++)
#pragma unroll
      for (int j = 0; j < WC; j++)
        acc[i][j] = __builtin_amdgcn_mfma_f32_16x16x32_bf16(bfr[j], af[i],
                                                            acc[i][j], 0, 0, 0);
    drain_all();
    __syncthreads();
  }

#pragma unroll
  for (int i = 0; i < WR; i++) {
    int row = m0 + wm + i * 16 + (lane & 15);
#pragma unroll
    for (int j = 0; j < WC; j++) {
      int col = n0 + wn + j * 16 + ((lane >> 4) << 2);
      float bv[4] = {0.f, 0.f, 0.f, 0.f};
      if (bias) {
        float4 b4 = *(const float4*)&bias[col];
        bv[0] = b4.x; bv[1] = b4.y; bv[2] = b4.z; bv[3] = b4.w;
      }
      float v[4];
#pragma unroll
      for (int r = 0; r < 4; r++) {
        v[r] = acc[i][j][r] + bv[r];
        if (ACT == 1) v[r] = fast_gelu(v[r]);
        else if (ACT == 2) v[r] = 1.0f / (1.0f + __expf(-v[r]));
      }
      size_t idx = (size_t)row * N + col;
      if constexpr (std::is_same<OUTT, float>::value) {
        *(float4*)&C[idx] = make_float4(v[0], v[1], v[2], v[3]);
      } else {
        uint2 u;
        bf16* h = (bf16*)&u;
#pragma unroll
        for (int r = 0; r < 4; r++) h[r] = __float2bfloat16(v[r]);
        *(uint2*)&C[idx] = u;
      }
    }
  }
}

// ---------------------------------------------- fused hi/lo triple core
// acc = Ah@Wh^T (+ Ah@Wl^T if fp) (+ Al@Wh^T if fp||ALWAYS_AL) + bias.
// Offset branch (index-critical). Single-buffered stage->drain->sync.
// SPLIT: epilogue applies exact erff-gelu and writes bf16 hi/lo pair.
template <int BM, int BN, bool SPLIT, bool ALWAYS_AL>
__device__ __forceinline__ void gemm3_core(
    bf16* smem, const bf16* Ah, const bf16* Al, const bf16* Wh,
    const bf16* Wl, const float* bias, int fp, float* Cf, bf16* Chi,
    bf16* Clo, int N, int K, int m0, int n0) {
  constexpr int WR = 2;
  constexpr int WC = (BM == 128) ? 4 : 2;
  bf16* Ash = smem;
  bf16* Asl = smem + BM * BK;
  bf16* Bsh = smem + 2 * BM * BK;
  bf16* Bsl = smem + 2 * BM * BK + BN * BK;
  const bool use_al = fp || ALWAYS_AL;
  const int tid = threadIdx.x;
  const int lane = tid & 63;
  const int wid = tid >> 6;
  int wm, wn;
  if constexpr (BM == 128) {
    wm = wid * 32; wn = 0;
  } else {
    wm = (wid >> 1) * 32; wn = (wid & 1) * 32;
  }

  floatx4 acc[WR][WC];
#pragma unroll
  for (int i = 0; i < WR; i++)
#pragma unroll
    for (int j = 0; j < WC; j++) acc[i][j] = (floatx4)0.0f;

  for (int kt = 0; kt < K; kt += BK) {
#pragma unroll
    for (int c = 0; c < BM / 64; c++) {
      int seg = c * 64 + wid * 16;
      int row = seg + (lane >> 2);
      int ch = (lane & 3) ^ ((row >> 1) & 3);
      size_t g = (size_t)(m0 + row) * K + kt + ch * 8;
      dma16(&Ah[g], &Ash[seg * BK]);
      if (use_al) dma16(&Al[g], &Asl[seg * BK]);
    }
#pragma unroll
    for (int c = 0; c < BN / 64; c++) {
      int seg = c * 64 + wid * 16;
      int row = seg + (lane >> 2);
      int ch = (lane & 3) ^ ((row >> 1) & 3);
      size_t g = (size_t)(n0 + row) * K + kt + ch * 8;
      dma16(&Wh[g], &Bsh[seg * BK]);
      if (fp) dma16(&Wl[g], &Bsl[seg * BK]);
    }
    drain_all();
    __syncthreads();
    const int kb = lane >> 4;
    short8 ah[WR], al[WR], bh[WC], bl[WC];
#pragma unroll
    for (int i = 0; i < WR; i++) {
      int r = wm + i * 16 + (lane & 15);
      int ro = r * BK + ((kb ^ ((r >> 1) & 3)) << 3);
      ah[i] = *(const short8*)(&Ash[ro]);
      if (use_al) al[i] = *(const short8*)(&Asl[ro]);
    }
#pragma unroll
    for (int j = 0; j < WC; j++) {
      int r = wn + j * 16 + (lane & 15);
      int ro = r * BK + ((kb ^ ((r >> 1) & 3)) << 3);
      bh[j] = *(const short8*)(&Bsh[ro]);
      if (fp) bl[j] = *(const short8*)(&Bsl[ro]);
    }
#pragma unroll
    for (int i = 0; i < WR; i++)
#pragma unroll
      for (int j = 0; j < WC; j++) {
        acc[i][j] = __builtin_amdgcn_mfma_f32_16x16x32_bf16(bh[j], ah[i],
                                                            acc[i][j], 0, 0, 0);
        if (fp)
          acc[i][j] = __builtin_amdgcn_mfma_f32_16x16x32_bf16(
              bl[j], ah[i], acc[i][j], 0, 0, 0);
        if (use_al)
          acc[i][j] = __builtin_amdgcn_mfma_f32_16x16x32_bf16(
              bh[j], al[i], acc[i][j], 0, 0, 0);
      }
    __syncthreads();
  }

#pragma unroll
  for (int i = 0; i < WR; i++) {
    int row = m0 + wm + i * 16 + (lane & 15);
#pragma unroll
    for (int j = 0; j < WC; j++) {
      int col = n0 + wn + j * 16 + ((lane >> 4) << 2);
      float4 b4 = *(const float4*)&bias[col];
      float bv[4] = {b4.x, b4.y, b4.z, b4.w};
      if constexpr (SPLIT) {
        uint2 uh, ul;
        bf16* hh = (bf16*)&uh;
        bf16* hl = (bf16*)&ul;
#pragma unroll
        for (int r = 0; r < 4; r++) {
          float v = acc[i][j][r] + bv[r];
          float g = 0.5f * v * (1.0f + erff(v * 0.70710678118654752f));
          bf16 hi = __float2bfloat16(g);
          hh[r] = hi;
          hl[r] = __float2bfloat16(g - __bfloat162float(hi));
        }
        *(uint2*)&Chi[(size_t)row * N + col] = uh;
        *(uint2*)&Clo[(size_t)row * N + col] = ul;
      } else {
        *(float4*)&Cf[(size_t)row * N + col] =
            make_float4(acc[i][j][0] + bv[0], acc[i][j][1] + bv[1],
                        acc[i][j][2] + bv[2], acc[i][j][3] + bv[3]);
      }
    }
  }
}

// ------------------------------------------------- GEMM wrappers
// qkv: N=3072 output; W segments selected per blockIdx.y. In bf16 mode the
// raw (unconcatenated) ip/dq/dk/dv pointers are used directly.
__global__ __launch_bounds__(256) void gemm_qkv(
    const bf16* __restrict__ xc, const void* __restrict__ xr,
    const bf16* __restrict__ wall, const void* __restrict__ ipr,
    const void* __restrict__ dqr, const void* __restrict__ dkr,
    const void* __restrict__ dvr, const float* __restrict__ ball,
    bf16* __restrict__ C, const int* __restrict__ meta) {
  __shared__ bf16 smem[2 * 256 * BK];
  int fp = meta[9];
  const bf16* A = fp ? xc : (const bf16*)xr;
  int y = blockIdx.y, n0 = y * 128, n0w;
  const bf16* W;
  if (fp) {
    W = wall; n0w = n0;
  } else if (y < 12) {
    W = (const bf16*)ipr; n0w = n0;
  } else {
    int s = (y - 12) >> 2;
    W = (const bf16*)(s == 0 ? dqr : s == 1 ? dkr : dvr);
    n0w = ((y - 12) & 3) * 128;
  }
  gemm_core<128, 128, 0, bf16>(smem, A, W, ball, C, 3072, kE,
                               blockIdx.x * 128, n0, n0w);
}

// generic single GEMM with device-side W (and optional A) passthrough
template <int BM, int BN, int ACT, typename OUTT>
__global__ __launch_bounds__(256) void gemm_sel(
    const bf16* __restrict__ A, const bf16* __restrict__ Wc,
    const void* __restrict__ Wr, const float* __restrict__ bias,
    OUTT* __restrict__ C, int N, int K, const int* __restrict__ meta) {
  __shared__ bf16 smem[2 * (BM + BN) * BK];
  const bf16* W = meta[9] ? Wc : (const bf16*)Wr;
  int n0 = blockIdx.y * BN;
  gemm_core<BM, BN, ACT, OUTT>(smem, A, W, bias, C, N, K, blockIdx.x * BM, n0,
                               n0);
}

// two independent E*E GEMMs in one launch (mha_out + do_out)
__global__ __launch_bounds__(256) void gemm_pair(
    const bf16* __restrict__ A0, const bf16* __restrict__ W0c,
    const void* __restrict__ W0r, const float* __restrict__ b0,
    bf16* __restrict__ C0, const bf16* __restrict__ A1,
    const bf16* __restrict__ W1c, const void* __restrict__ W1r,
    const float* __restrict__ b1, bf16* __restrict__ C1, int N, int K,
    const int* __restrict__ meta) {
  __shared__ bf16 smem[2 * (128 + 64) * BK];
  int fp = meta[9];
  int nb = N >> 6;
  bool s = (int)blockIdx.y >= nb;
  const bf16* W = s ? (fp ? W1c : (const bf16*)W1r)
                    : (fp ? W0c : (const bf16*)W0r);
  int n0 = (s ? (int)blockIdx.y - nb : (int)blockIdx.y) * 64;
  gemm_core<128, 64, 0, bf16>(smem, s ? A1 : A0, W, s ? b1 : b0, s ? C1 : C0,
                              N, K, blockIdx.x * 128, n0, n0);
}

// o1 offset triple: h = gelu(x@o1w^T+b), bf16 hi/lo split epilogue.
__global__ __launch_bounds__(256) void gemm_o1(
    const bf16* __restrict__ xc, const void* __restrict__ xr,
    const bf16* __restrict__ x_lo, const bf16* __restrict__ o1hc,
    const void* __restrict__ o1r, const bf16* __restrict__ o1l,
    const float* __restrict__ o1b, const int* __restrict__ meta,
    bf16* __restrict__ h_hi, bf16* __restrict__ h_lo) {
  __shared__ bf16 smem[(2 * 128 + 2 * 64) * BK];  // 24KB
  int fp = meta[9];
  gemm3_core<128, 64, true, false>(
      smem, fp ? xc : (const bf16*)xr, x_lo, fp ? o1hc : (const bf16*)o1r,
      o1l, o1b, fp, nullptr, h_hi, h_lo, kE, kE, blockIdx.x * 128,
      blockIdx.y * 64);
}

// o2 offset triple: rawf = h@o2w^T + b (fp32; h_lo term always on).
__global__ __launch_bounds__(256) void gemm_o2(
    const bf16* __restrict__ h_hi, const bf16* __restrict__ h_lo,
    const bf16* __restrict__ o2hc, const void* __restrict__ o2r,
    const bf16* __restrict__ o2l, const float* __restrict__ o2b,
    const int* __restrict__ meta, float* __restrict__ rawf) {
  __shared__ bf16 smem[4 * 64 * BK];  // 16KB
  int fp = meta[9];
  gemm3_core<64, 64, false, true>(smem, h_hi, h_lo,
                                  fp ? o2hc : (const bf16*)o2r, o2l, o2b, fp,
                                  rawf, nullptr, nullptr, 256, kE,
                                  blockIdx.x * 64, blockIdx.y * 64);
}

// gate1: A is virtual concat [x | local_out | long_out] (K=1536), gelu act.
__global__ __launch_bounds__(256) void gemm_gate1(
    const bf16* __restrict__ xc, const void* __restrict__ xr,
    const bf16* __restrict__ lo, const bf16* __restrict__ lg,
    const bf16* __restrict__ Wc, const void* __restrict__ Wr,
    const float* __restrict__ bias, bf16* __restrict__ C,
    const int* __restrict__ meta) {
  constexpr int BM = 128, BN = 64, WR = 2, WC = 4;
  constexpr int N = 512, K = 1536;
  __shared__ bf16 As[2][BM * BK];
  __shared__ bf16 Bs[2][BN * BK];
  int fp = meta[9];
  const bf16* x = fp ? xc : (const bf16*)xr;
  const bf16* W = fp ? Wc : (const bf16*)Wr;
  const int tid = threadIdx.x;
  const int lane = tid & 63;
  const int wid = tid >> 6;
  const int wm = wid * 32, wn = 0;
  const int m0 = blockIdx.x * BM, n0 = blockIdx.y * BN;

  auto stage = [&](int buf, int kt) {
    const bf16* src = (kt < 512) ? x : (kt < 1024) ? lo : lg;
    int kk = kt & 511;
#pragma unroll
    for (int c = 0; c < 2; c++) {
      int seg = c * 64 + wid * 16;
      int row = seg + (lane >> 2);
      int ch = (lane & 3) ^ ((row >> 1) & 3);
      dma16(&src[(size_t)(m0 + row) * 512 + kk + ch * 8], &As[buf][seg * BK]);
    }
    {
      int seg = wid * 16;
      int row = seg + (lane >> 2);
      int ch = (lane & 3) ^ ((row >> 1) & 3);
      dma16(&W[(size_t)(n0 + row) * K + kt + ch * 8], &Bs[buf][seg * BK]);
    }
  };

  floatx4 acc[WR][WC];
#pragma unroll
  for (int i = 0; i < WR; i++)
#pragma unroll
    for (int j = 0; j < WC; j++) acc[i][j] = (floatx4)0.0f;

  stage(0, 0);
  drain_all();
  __syncthreads();
  const int niter = K / BK;
  for (int k = 0; k < niter; k++) {
    const int cur = k & 1;
    if (k + 1 < niter) stage(cur ^ 1, (k + 1) * BK);
    const int kb = lane >> 4;
    short8 af[WR], bfr[WC];
#pragma unroll
    for (int i = 0; i < WR; i++) {
      int r = wm + i * 16 + (lane & 15);
      af[i] = *(const short8*)(&As[cur][r * BK + ((kb ^ ((r >> 1) & 3)) << 3)]);
    }
#pragma unroll
    for (int j = 0; j < WC; j++) {
      int r = wn + j * 16 + (lane & 15);
      bfr[j] = *(const short8*)(&Bs[cur][r * BK + ((kb ^ ((r >> 1) & 3)) << 3)]);
    }
#pragma unroll
    for (int i = 0; i < WR; i++)
#pragma unroll
      for (int j = 0; j < WC; j++)
        acc[i][j] = __builtin_amdgcn_mfma_f32_16x16x32_bf16(bfr[j], af[i],
                                                            acc[i][j], 0, 0, 0);
    drain_all();
    __syncthreads();
  }

#pragma unroll
  for (int i = 0; i < WR; i++) {
    int row = m0 + wm + i * 16 + (lane & 15);
#pragma unroll
    for (int j = 0; j < WC; j++) {
      int col = n0 + wn + j * 16 + ((lane >> 4) << 2);
      float4 b4 = *(const float4*)&bias[col];
      float bv[4] = {b4.x, b4.y, b4.z, b4.w};
      uint2 u;
      bf16* h = (bf16*)&u;
#pragma unroll
      for (int r = 0; r < 4; r++)
        h[r] = __float2bfloat16(fast_gelu(acc[i][j][r] + bv[r]));
      *(uint2*)&C[(size_t)row * N + col] = u;
    }
  }
}

// ------------------------------------------------------- local attention
// qkv_all row stride 3072: [q 0:512 | k 512:1024 | v 1024:1536 | qd|kd|vd]
__global__ __launch_bounds__(256) void local_attn_kernel(
    const bf16* __restrict__ qkv, const void* __restrict__ pm,
    const int* __restrict__ meta, bf16* __restrict__ lo) {
  int lane = threadIdx.x & 63;
  int t = blockIdx.x * 4 + (threadIdx.x >> 6);
  int b = t >> 10, s = t & 1023;
  int h = lane >> 3, sub = lane & 7;
  int flag = meta[0];
  float q[8];
  load8f(qkv + (size_t)t * 3072 + h * 64 + sub * 8, q);
  float sc[4];
  bool val[4];
#pragma unroll
  for (int w = 0; w < 4; w++) {
    int kp = s - 3 + w;
    bool v = (kp >= 0) && !is_pad(pm, flag, b * kS + kp);
    float d = 0.0f;
    if (v) {
      float kk[8];
      load8f(qkv + (size_t)(b * kS + kp) * 3072 + 512 + h * 64 + sub * 8, kk);
#pragma unroll
      for (int e = 0; e < 8; e++) d += q[e] * kk[e];
    }
    d += __shfl_xor(d, 1);
    d += __shfl_xor(d, 2);
    d += __shfl_xor(d, 4);
    sc[w] = v ? d / 8.0f : -INFINITY;
    val[w] = v;
  }
  float mx = fmaxf(fmaxf(sc[0], sc[1]), fmaxf(sc[2], sc[3]));
  float a[4] = {0.f, 0.f, 0.f, 0.f};
  if (mx != -INFINITY) {
    float ssum = 0.f;
#pragma unroll
    for (int w = 0; w < 4; w++) {
      float e = val[w] ? expf(sc[w] - mx) : 0.0f;
      a[w] = e;
      ssum += e;
    }
#pragma unroll
    for (int w = 0; w < 4; w++) a[w] /= ssum;
  }
  float o[8] = {0.f, 0.f, 0.f, 0.f, 0.f, 0.f, 0.f, 0.f};
#pragma unroll
  for (int w = 0; w < 4; w++) {
    if (val[w] && a[w] > 0.0f) {
      int kp = s - 3 + w;
      float vv[8];
      load8f(qkv + (size_t)(b * kS + kp) * 3072 + 1024 + h * 64 + sub * 8, vv);
#pragma unroll
      for (int e = 0; e < 8; e++) o[e] += a[w] * vv[e];
    }
  }
  store8b(lo + (size_t)t * kE + lane * 8, o);
}

// ------------------- long attention with INLINE sampler (one wave/token)
// qkv_all: qd at +1536, kd at +2048, vd at +2560 (stride 3072).
__global__ __launch_bounds__(256) void long_attn_kernel(
    const bf16* __restrict__ qkv, const float* __restrict__ rawf,
    const void* __restrict__ pm, const int* __restrict__ meta,
    bf16* __restrict__ ctx) {
  int lane = threadIdx.x & 63;
  int bid = blockIdx.x;
  int sbid = (bid & 7) * 256 + (bid >> 3);  // XCD-contiguous token ranges
  int t = sbid * 4 + (threadIdx.x >> 6);
  int b = t >> 10, s = t & 1023;
  int flag = meta[0];
  int p = lane & 31;
  // ---- inline sampler (both wave halves compute identical values for p)
  float off = 0.0f;
#pragma unroll
  for (int h = 0; h < kH; h++) off += tanhf(rawf[(size_t)t * 256 + h * kP + p]);
  double anchor = 0.1 + 0.8 * (double)p / 31.0;
  double sampled = anchor * (double)s + (double)off;
  double lov = fmax(0.0, (double)s - 256.0);
  sampled = fmin(fmax(sampled, lov), (double)s);
  int vlen = meta[1 + b];
  sampled = fmin(sampled, (double)(vlen - 1));
  int spv = (int)rint(sampled);  // half-to-even, matches np.round
  bool inv = is_pad(pm, flag, b * kS + spv) || (spv > s) ||
             (spv >= max(0, s - 3));
  int row_abs = b * kS + spv;
  // ---- QK: per-sample coalesced K-row load + butterfly reduce
  float q[8];
  load8f(qkv + (size_t)t * 3072 + 1536 + lane * 8, q);
  float sc_mine = 0.0f;
#pragma unroll 4
  for (int pp = 0; pp < 32; pp++) {
    int row = __shfl(row_abs, pp);
    float kk[8];
    load8f(qkv + (size_t)row * 3072 + 2048 + lane * 8, kk);
    float d = 0.0f;
#pragma unroll
    for (int e = 0; e < 8; e++) d += q[e] * kk[e];
#pragma unroll
    for (int m = 1; m < 64; m <<= 1) d += __shfl_xor(d, m);
    if (p == pp) sc_mine = d;
  }
  float sc = inv ? -INFINITY : sc_mine / 22.627416997969522f;  // sqrt(512)
  float mx = sc;
#pragma unroll
  for (int m = 1; m < 32; m <<= 1) mx = fmaxf(mx, __shfl_xor(mx, m));
  float e = (inv || mx == -INFINITY) ? 0.0f : expf(sc - mx);
  float ssum = e;
#pragma unroll
  for (int m = 1; m < 32; m <<= 1) ssum += __shfl_xor(ssum, m);
  float a = (ssum > 0.0f) ? e / ssum : 0.0f;
  float o[8] = {0.f, 0.f, 0.f, 0.f, 0.f, 0.f, 0.f, 0.f};
#pragma unroll 4
  for (int pp = 0; pp < 32; pp++) {
    float ap = __shfl(a, pp);
    int row = __shfl(row_abs, pp);
    if (ap != 0.0f) {
      float vv[8];
      load8f(qkv + (size_t)row * 3072 + 2560 + lane * 8, vv);
#pragma unroll
      for (int e2 = 0; e2 < 8; e2++) o[e2] += ap * vv[e2];
    }
  }
  store8b(ctx + (size_t)t * kE + lane * 8, o);
}

// ------------------------------------------------------------------- LN1
__global__ __launch_bounds__(256) void ln1_kernel(
    const void* __restrict__ xin, const int* __restrict__ meta,
    const bf16* __restrict__ lo, const bf16* __restrict__ lg,
    const bf16* __restrict__ g, const float* __restrict__ gamma,
    const float* __restrict__ beta, bf16* __restrict__ x1b,
    float* __restrict__ x1f) {
  int lane = threadIdx.x & 63;
  int t = blockIdx.x * 4 + (threadIdx.x >> 6);
  size_t base = (size_t)t * kE + lane * 8;
  float xv[8], lov[8], lgv[8], gv[8], h[8];
  if (meta[9]) {
    const float4* xf = (const float4*)((const float*)xin + base);
    float4 a = xf[0], b2 = xf[1];
    xv[0] = a.x; xv[1] = a.y; xv[2] = a.z; xv[3] = a.w;
    xv[4] = b2.x; xv[5] = b2.y; xv[6] = b2.z; xv[7] = b2.w;
  } else {
    load8f((const bf16*)xin + base, xv);
  }
  load8f(lo + base, lov);
  load8f(lg + base, lgv);
  load8f(g + base, gv);
  float s1 = 0.f, s2 = 0.f;
#pragma unroll
  for (int e = 0; e < 8; e++) {
    h[e] = xv[e] + gv[e] * lov[e] + (1.0f - gv[e]) * lgv[e];
    s1 += h[e];
    s2 += h[e] * h[e];
  }
#pragma unroll
  for (int m = 1; m < 64; m <<= 1) {
    s1 += __shfl_xor(s1, m);
    s2 += __shfl_xor(s2, m);
  }
  float mean = s1 * (1.0f / kE);
  float var = s2 * (1.0f / kE) - mean * mean;
  float rstd = 1.0f / sqrtf(var + 1e-5f);
  float y[8];
#pragma unroll
  for (int e = 0; e < 8; e++)
    y[e] = (h[e] - mean) * rstd * gamma[lane * 8 + e] + beta[lane * 8 + e];
  store8b(x1b + base, y);
#pragma unroll
  for (int e = 0; e < 8; e++) x1f[base + e] = y[e];
}

// ------------------------------------------------------------------- LN2
__global__ __launch_bounds__(256) void ln2_kernel(
    const float* __restrict__ x1f, const float* __restrict__ ff,
    const float* __restrict__ gamma, const float* __restrict__ beta,
    const int* __restrict__ meta, void* __restrict__ out) {
  int lane = threadIdx.x & 63;
  int t = blockIdx.x * 4 + (threadIdx.x >> 6);
  size_t base = (size_t)t * kE + lane * 8;
  float h[8];
  float s1 = 0.f, s2 = 0.f;
#pragma unroll
  for (int e = 0; e < 8; e++) {
    h[e] = x1f[base + e] + ff[base + e];
    s1 += h[e];
    s2 += h[e] * h[e];
  }
#pragma unroll
  for (int m = 1; m < 64; m <<= 1) {
    s1 += __shfl_xor(s1, m);
    s2 += __shfl_xor(s2, m);
  }
  float mean = s1 * (1.0f / kE);
  float var = s2 * (1.0f / kE) - mean * mean;
  float rstd = 1.0f / sqrtf(var + 1e-5f);
  float y[8];
#pragma unroll
  for (int e = 0; e < 8; e++)
    y[e] = (h[e] - mean) * rstd * gamma[lane * 8 + e] + beta[lane * 8 + e];
  if (meta[9]) {
    float* of = (float*)out + base;
    ((float4*)of)[0] = make_float4(y[0], y[1], y[2], y[3]);
    ((float4*)of)[1] = make_float4(y[4], y[5], y[6], y[7]);
  } else {
    store8b((bf16*)out + base, y);
  }
}

// ------------------------------------------------------------------ launch
extern "C" void kernel_launch(void* const* d_in, const int* in_sizes, int n_in,
                              void* d_out, int out_size, void* d_ws,
                              size_t ws_size, hipStream_t stream) {
  const void* x = d_in[0];
  const void* pm = d_in[1];

  char* w = (char*)d_ws;
  auto alloc = [&](size_t bytes) {
    char* p = w;
    w += (bytes + 255) & ~(size_t)255;
    return p;
  };
  bf16* qkv_all = (bf16*)alloc((size_t)kTok * 3072 * 2);  // recycled later
  bf16* lo_ctx = (bf16*)alloc((size_t)kTok * kE * 2);
  bf16* ctx2 = (bf16*)alloc((size_t)kTok * kE * 2);
  bf16* local_out = (bf16*)alloc((size_t)kTok * kE * 2);
  bf16* long_out = (bf16*)alloc((size_t)kTok * kE * 2);
  bf16* hbuf = (bf16*)alloc((size_t)kTok * kE * 2);    // h_hi / gate hidden
  bf16* gbuf = (bf16*)alloc((size_t)kTok * kE * 2);    // gate out
  bf16* x1b = (bf16*)alloc((size_t)kTok * kE * 2);     // h_lo / x1 bf16
  float* x1f = (float*)alloc((size_t)kTok * kE * 4);   // x1 fp32
  float* rawf = (float*)alloc((size_t)kTok * 256 * 4);
  int* meta = (int*)alloc(256);
  bf16* x_hi = (bf16*)alloc((size_t)kTok * kE * 2);
  bf16* x_lo = (bf16*)alloc((size_t)kTok * kE * 2);
  bf16* wall = (bf16*)alloc((size_t)3072 * 512 * 2);  // ip|dq|dk|dv (fp mode)
  bf16* mow = (bf16*)alloc(512 * 512 * 2);
  bf16* dow = (bf16*)alloc(512 * 512 * 2);
  bf16* o1h = (bf16*)alloc(512 * 512 * 2);
  bf16* o1l = (bf16*)alloc(512 * 512 * 2);
  bf16* o2h = (bf16*)alloc(256 * 512 * 2);
  bf16* o2l = (bf16*)alloc(256 * 512 * 2);
  bf16* g1w = (bf16*)alloc(512 * 1536 * 2);
  bf16* g2w = (bf16*)alloc(512 * 512 * 2);
  bf16* f1w = (bf16*)alloc((size_t)2048 * 512 * 2);
  bf16* f2w = (bf16*)alloc((size_t)512 * 2048 * 2);
  float* ball = (float*)alloc(3072 * 4);
  float* mob = (float*)alloc(512 * 4);
  float* dob = (float*)alloc(512 * 4);
  float* o1b = (float*)alloc(512 * 4);
  float* o2b = (float*)alloc(256 * 4);
  float* g1b = (float*)alloc(512 * 4);
  float* g2b = (float*)alloc(512 * 4);
  float* n1g = (float*)alloc(512 * 4);
  float* n1bt = (float*)alloc(512 * 4);
  float* n2g = (float*)alloc(512 * 4);
  float* n2bt = (float*)alloc(512 * 4);
  float* f1b = (float*)alloc(2048 * 4);
  float* f2b = (float*)alloc(512 * 4);

  bf16* h_hi = hbuf;
  bf16* h_lo = x1b;
  float* f_f32 = (float*)qkv_all;                                 // 16.8MB
  bf16* ffn_h = (bf16*)((char*)qkv_all + (size_t)kTok * kE * 4);  // 33.5MB

  dim3 blk(256);
  detect_meta_kernel<<<1, blk, 0, stream>>>(x, pm, meta);

  // ---- combined ingest (one launch; near-no-op in bf16 passthrough mode)
  CvtJobs J;
  auto job = [](const void* s, bf16* hi, bf16* lo, int n) {
    CvtJob j; j.src = s; j.hi = hi; j.lo = lo; j.nblk = n >> 10; return j;
  };
  J.j[0] = job(d_in[0], x_hi, x_lo, kTok * kE);
  J.j[1] = job(d_in[2], wall, nullptr, 1536 * 512);
  J.j[2] = job(d_in[6], wall + (size_t)1536 * 512, nullptr, 512 * 512);
  J.j[3] = job(d_in[8], wall + (size_t)2048 * 512, nullptr, 512 * 512);
  J.j[4] = job(d_in[10], wall + (size_t)2560 * 512, nullptr, 512 * 512);
  J.j[5] = job(d_in[4], mow, nullptr, 512 * 512);
  J.j[6] = job(d_in[12], dow, nullptr, 512 * 512);
  J.j[7] = job(d_in[14], o1h, o1l, 512 * 512);
  J.j[8] = job(d_in[16], o2h, o2l, 256 * 512);
  J.j[9] = job(d_in[18], g1w, nullptr, 512 * 1536);
  J.j[10] = job(d_in[20], g2w, nullptr, 512 * 512);
  J.j[11] = job(d_in[26], f1w, nullptr, 2048 * 512);
  J.j[12] = job(d_in[28], f2w, nullptr, 512 * 2048);
  int totblk = 0;
  for (int i = 0; i < 13; i++) totblk += J.j[i].nblk;

  CvtFJobs JF;
  auto fjob = [](const void* s, float* d, int n) {
    CvtFJob j; j.src = s; j.dst = d; j.n = n; return j;
  };
  JF.j[0] = fjob(d_in[3], ball, 1536);
  JF.j[1] = fjob(d_in[7], ball + 1536, 512);
  JF.j[2] = fjob(d_in[9], ball + 2048, 512);
  JF.j[3] = fjob(d_in[11], ball + 2560, 512);
  JF.j[4] = fjob(d_in[5], mob, 512);
  JF.j[5] = fjob(d_in[13], dob, 512);
  JF.j[6] = fjob(d_in[15], o1b, 512);
  JF.j[7] = fjob(d_in[17], o2b, 256);
  JF.j[8] = fjob(d_in[19], g1b, 512);
  JF.j[9] = fjob(d_in[21], g2b, 512);
  JF.j[10] = fjob(d_in[22], n1g, 512);
  JF.j[11] = fjob(d_in[23], n1bt, 512);
  JF.j[12] = fjob(d_in[24], n2g, 512);
  JF.j[13] = fjob(d_in[25], n2bt, 512);
  JF.j[14] = fjob(d_in[27], f1b, 2048);
  JF.j[15] = fjob(d_in[29], f2b, 512);
  cvt_all_kernel<<<totblk + 1, blk, 0, stream>>>(J, JF, totblk, meta);

  // ---- merged qkv + deformable-qkv projection (N=3072, segmented W)
  gemm_qkv<<<dim3(64, 24), blk, 0, stream>>>(x_hi, x, wall, d_in[2], d_in[6],
                                             d_in[8], d_in[10], ball, qkv_all,
                                             meta);
  // ---- offset branch (hi/lo triples, raw passthrough in bf16 mode)
  gemm_o1<<<dim3(64, 8), blk, 0, stream>>>(x_hi, x, x_lo, o1h, d_in[14], o1l,
                                           o1b, meta, h_hi, h_lo);
  local_attn_kernel<<<2048, blk, 0, stream>>>(qkv_all, pm, meta, lo_ctx);
  gemm_o2<<<dim3(128, 4), blk, 0, stream>>>(h_hi, h_lo, o2h, d_in[16], o2l,
                                            o2b, meta, rawf);
  // ---- long attention with inline sampler
  long_attn_kernel<<<2048, blk, 0, stream>>>(qkv_all, rawf, pm, meta, ctx2);

  // ---- both attention output projections in one launch
  gemm_pair<<<dim3(64, 16), blk, 0, stream>>>(lo_ctx, mow, d_in[4], mob,
                                              local_out, ctx2, dow, d_in[12],
                                              dob, long_out, kE, kE, meta);

  // ---- gate (virtual concat in gate1 staging)
  gemm_gate1<<<dim3(64, 8), blk, 0, stream>>>(x_hi, x, local_out, long_out,
                                              g1w, d_in[18], g1b, hbuf, meta);
  gemm_sel<128, 64, 2, bf16><<<dim3(64, 8), blk, 0, stream>>>(
      hbuf, g2w, d_in[20], g2b, gbuf, kE, kE, meta);

  // ---- fuse + LN1 + FFN + LN2
  ln1_kernel<<<2048, blk, 0, stream>>>(x, meta, local_out, long_out, gbuf, n1g,
                                       n1bt, x1b, x1f);
  gemm_sel<128, 128, 1, bf16><<<dim3(64, 16), blk, 0, stream>>>(
      x1b, f1w, d_in[26], f1b, ffn_h, kHid, kE, meta);
  gemm_sel<128, 64, 0, float><<<dim3(64, 8), blk, 0, stream>>>(
      ffn_h, f2w, d_in[28], f2b, f_f32, kE, kHid, meta);
  ln2_kernel<<<2048, blk, 0, stream>>>(x1f, f_f32, n2g, n2bt, meta, d_out);
}